// Round 18
// baseline (586.761 us; speedup 1.0000x reference)
//
#include <hip/hip_runtime.h>
#include <hip/hip_bf16.h>

// BasicBlock via chunked shift-GEMM bf16 MFMA. R17: BARRIER-FREE direct-
// global B. R4-R16 all pinned at ~36% MfmaUtil (m97/m233 plateau): the
// barriered LDS-window keeps all waves in lockstep so stalls correlate;
// no single pipe >40%. Fix: B-frags load straight from xT/yT [n][p][ci]
// (16B/lane contiguous; per-chunk working set 12KB -> L1-resident, 9x tap
// reuse). Tap shift = compile-time byte imm; chunk advance = uniform c*64;
// border mask = address-select to a global zero-row after each image
// array. ZERO barriers in the K-loop; no LDS staging; no bank conflicts.
// Keeps: frag-packed weights w/ depth-2 A prefetch (areg[3], s%3 rotation
// aligned since 9%3==0), 1-tap bq dbuf (named arrays), setprio, XCD
// swizzle, rolled per-chunk loop (I-cache resident).

typedef __attribute__((ext_vector_type(8))) short bf16x8;
typedef __attribute__((ext_vector_type(4))) float f32x4;
typedef __attribute__((ext_vector_type(4))) unsigned int uint4v;

#define C_CH   256
#define HW_IMG 3136
#define CHW    802816     // 256*3136
#define WELEM  589824     // 256*2304
#define ZBELEM 25690112   // 32*HW_IMG*256: zero-row offset after image array

__device__ __forceinline__ ushort f2bf(float f){
    union{__hip_bfloat16 h; ushort u;} c; c.h = __float2bfloat16(f); return c.u;
}

__global__ __launch_bounds__(256) void prep_kernel(
    const float* __restrict__ w1, const float* __restrict__ w2,
    const float* __restrict__ g1, const float* __restrict__ b1,
    const float* __restrict__ m1, const float* __restrict__ v1,
    const float* __restrict__ g2, const float* __restrict__ b2,
    const float* __restrict__ m2, const float* __restrict__ v2,
    ushort* __restrict__ wf1, ushort* __restrict__ wf2,
    float* __restrict__ bn, ushort* __restrict__ xzb, ushort* __restrict__ yzb)
{
    int gid = blockIdx.x * 256 + threadIdx.x;
    // frag-packed: d = (((c*9+r)*16 + ct)*64 + l)*8 + j
    // co = ct*16 + (l&15), ci = c*32 + (l>>4)*8 + j, tap r
    if (gid < WELEM) {
        int j = gid & 7, l = (gid >> 3) & 63, ct = (gid >> 9) & 15, rr = gid >> 13;
        int c = rr / 9, r = rr - c * 9;
        int co = ct * 16 + (l & 15);
        int ci = c * 32 + (l >> 4) * 8 + j;
        wf1[gid] = f2bf(w1[(co * C_CH + ci) * 9 + r]);
    }
    int g2i = gid - WELEM;
    if (g2i >= 0 && g2i < WELEM) {
        int j = g2i & 7, l = (g2i >> 3) & 63, ct = (g2i >> 9) & 15, rr = g2i >> 13;
        int c = rr / 9, r = rr - c * 9;
        int co = ct * 16 + (l & 15);
        int ci = c * 32 + (l >> 4) * 8 + j;
        wf2[g2i] = f2bf(w2[(co * C_CH + ci) * 9 + r]);
    }
    if (gid < C_CH) {
        float i1 = g1[gid] * rsqrtf(v1[gid] + 1e-5f);
        bn[gid]            = i1;
        bn[C_CH + gid]     = b1[gid] - m1[gid] * i1;
        float i2 = g2[gid] * rsqrtf(v2[gid] + 1e-5f);
        bn[2*C_CH + gid]   = i2;
        bn[3*C_CH + gid]   = b2[gid] - m2[gid] * i2;
    }
    if (gid < 512) { xzb[gid] = 0; yzb[gid] = 0; }
}

// x [n][ci][p] f32 -> xT [n][p][ci] bf16
__global__ __launch_bounds__(256) void xpose_kernel(
    const float* __restrict__ x, ushort* __restrict__ xT)
{
    __shared__ ushort T[64 * 72];
    int tid = threadIdx.x;
    int b = blockIdx.x;                  // 32*49*4
    int n = b / 196, rem = b % 196;
    int pb = rem >> 2, cb = rem & 3;
    int lane = tid & 63, cr = tid >> 6;
    const float* xp = x + ((size_t)(n * C_CH + cb * 64)) * HW_IMG + pb * 64 + lane;
#pragma unroll
    for (int j = 0; j < 16; ++j) {
        int cil = cr * 16 + j;
        T[lane * 72 + cil] = f2bf(xp[(size_t)cil * HW_IMG]);
    }
    __syncthreads();
#pragma unroll
    for (int it = 0; it < 2; ++it) {
        int slot = it * 256 + tid;       // 512 slots = 64 rows x 8 granules
        int p = slot >> 3, g = slot & 7;
        uint4v v = *(const uint4v*)&T[p * 72 + g * 8];
        *(uint4v*)(xT + ((size_t)n * HW_IMG + pb * 64 + p) * C_CH + cb * 64 + g * 8) = v;
    }
}

// read tap s's 4 B-frags DIRECT from global (address-select to zero row)
#define READB_G(dstq, s, cbytes)                                             \
    {                                                                        \
        const int dh_ = (s) / 3 - 1, dw_ = (s) % 3 - 1;                      \
        const int off_ = (dh_ * 56 + dw_) * 512;   /* bytes */               \
        _Pragma("unroll")                                                    \
        for (int nc_ = 0; nc_ < 4; ++nc_) {                                  \
            bool ok_ = ((dh_ == -1) ? hU[nc_] : (dh_ == 1) ? hD[nc_] : true) \
                    && ((dw_ == -1) ? wL[nc_] : (dw_ == 1) ? wR[nc_] : true);\
            uint vo_ = ok_ ? (vb[nc_] + (uint)off_ + (cbytes)) : zo;         \
            dstq[nc_] = *(const bf16x8*)(sIb + vo_);                         \
        }                                                                    \
    }

// MFMA cluster; s = chunk-relative step (0..8, compile-time); t%3 == s%3
#define MFMA16(bq, s)                                                        \
    __builtin_amdgcn_s_setprio(1);                                           \
    _Pragma("unroll")                                                        \
    for (int mr_ = 0; mr_ < 4; ++mr_) {                                      \
        _Pragma("unroll")                                                    \
        for (int nc_ = 0; nc_ < 4; ++nc_)                                    \
            acc[mr_][nc_] = __builtin_amdgcn_mfma_f32_16x16x32_bf16(         \
                areg[(s) % 3][mr_], bq[nc_], acc[mr_][nc_], 0, 0, 0);        \
    }                                                                        \
    __builtin_amdgcn_s_setprio(0);

// load A-frags for chunk-relative step `toff` from chunk base pW
#define LOADA(toff, slot)                                                    \
    {                                                                        \
        _Pragma("unroll")                                                    \
        for (int mr_ = 0; mr_ < 4; ++mr_)                                    \
            areg[slot][mr_] = *(const bf16x8*)(pW + (toff) * 8192 + mr_ * 512);\
    }

template<bool SECOND>
__global__ __launch_bounds__(256, 2) void conv_kernel(
    const ushort* __restrict__ srcT,    // [n][p][ci] bf16 (+zero row at ZBELEM)
    const ushort* __restrict__ wf,      // frag-packed weights
    const float* __restrict__ bnp,      // inv | add
    const float* __restrict__ ident,    // x fp32 (conv2)
    void* __restrict__ dst)
{
    __shared__ ushort T[16896];         // conv1 epilogue transpose only

    const int tid = threadIdx.x;
    const int wv = tid >> 6, l = tid & 63;
    const int lr = l & 15, lg = l >> 4;

    int bid = blockIdx.x;
    int swz = (bid & 7) * 196 + (bid >> 3);   // XCD-chunked, bijective (1568=8*196)
    const int n = swz / 49, pt = swz % 49;
    const int p0 = pt * 64;

    // per-nc border validity + base byte-offsets into this image's [p][ci]
    bool wL[4], wR[4], hU[4], hD[4];
    uint vb[4];
#pragma unroll
    for (int nc = 0; nc < 4; ++nc) {
        int p = p0 + nc * 16 + lr;
        int w = p % 56;
        wL[nc] = (w > 0);
        wR[nc] = (w < 55);
        hU[nc] = (p >= 56);
        hD[nc] = (p < HW_IMG - 56);
        vb[nc] = (uint)(p * 512 + lg * 16);
    }
    const char* sIb = (const char*)(srcT + (size_t)n * HW_IMG * C_CH);
    const uint  zo  = (uint)((size_t)(32 - n) * HW_IMG * 512) + (uint)(lg * 16);

    f32x4 acc[4][4];
#pragma unroll
    for (int mr = 0; mr < 4; ++mr)
#pragma unroll
        for (int nc = 0; nc < 4; ++nc) {
            f32x4 z = {0.f, 0.f, 0.f, 0.f};
            acc[mr][nc] = z;
        }

    bf16x8 areg[3][4];
    const ushort* pW0 = wf + wv * 2048 + l * 8;   // + (c*9+s)*8192 + mr*512

    // prologue A (chunk 0, steps 0,1)
    {
        const ushort* pW = pW0;
        LOADA(0, 0);
        LOADA(1, 1);
    }

    // 8 runtime chunk iterations, 9 compile-time steps each; NO barriers.
#pragma unroll 1
    for (int c = 0; c < 8; ++c) {
        const uint cbytes = (uint)(c * 64);
        const ushort* pW = pW0 + (size_t)c * 9 * 8192;
        bf16x8 bqA[4], bqB[4];
        READB_G(bqA, 0, cbytes);
#pragma unroll
        for (int s = 0; s < 9; ++s) {
            if (s < 7 || c < 7) LOADA(s + 2, (s + 2) % 3);
            if ((s & 1) == 0) {
                if (s + 1 < 9) READB_G(bqB, s + 1, cbytes);
                MFMA16(bqA, s);
            } else {
                READB_G(bqA, s + 1, cbytes);    // s+1 <= 8
                MFMA16(bqB, s);
            }
        }
    }

    if constexpr (!SECOND) {
        // epilogue: BN+ReLU, LDS-transpose to yT [n][p][co] bf16
#pragma unroll
        for (int mr = 0; mr < 4; ++mr) {
#pragma unroll
            for (int nc = 0; nc < 4; ++nc) {
                int co0 = wv * 64 + mr * 16 + lg * 4;
                float v0 = fmaxf(acc[mr][nc][0] * bnp[co0+0] + bnp[C_CH+co0+0], 0.f);
                float v1 = fmaxf(acc[mr][nc][1] * bnp[co0+1] + bnp[C_CH+co0+1], 0.f);
                float v2 = fmaxf(acc[mr][nc][2] * bnp[co0+2] + bnp[C_CH+co0+2], 0.f);
                float v3 = fmaxf(acc[mr][nc][3] * bnp[co0+3] + bnp[C_CH+co0+3], 0.f);
                uint2 pk;
                pk.x = (uint)f2bf(v0) | ((uint)f2bf(v1) << 16);
                pk.y = (uint)f2bf(v2) | ((uint)f2bf(v3) << 16);
                *(uint2*)&T[(nc * 16 + lr) * 264 + co0] = pk;
            }
        }
        __syncthreads();
        ushort* yT = (ushort*)dst;
#pragma unroll
        for (int it = 0; it < 8; ++it) {
            int slot = it * 256 + tid;  // 2048 slots = 64 rows x 32 granules
            int row = slot >> 5, g = slot & 31;
            uint4v v = *(const uint4v*)&T[row * 264 + g * 8];
            *(uint4v*)(yT + ((size_t)n * HW_IMG + p0 + row) * C_CH + g * 8) = v;
        }
    } else {
        // epilogue: BN + identity + ReLU, fp32 out [n][co][p]
        const size_t nbase = (size_t)n * CHW;
        float* out = (float*)dst;
#pragma unroll
        for (int mr = 0; mr < 4; ++mr) {
#pragma unroll
            for (int nc = 0; nc < 4; ++nc) {
                int pc = p0 + nc * 16 + lr;
#pragma unroll
                for (int i = 0; i < 4; ++i) {
                    int co = wv * 64 + mr * 16 + lg * 4 + i;
                    size_t o = nbase + (size_t)co * HW_IMG + pc;
                    float val = acc[mr][nc][i] * bnp[co] + bnp[C_CH + co] + ident[o];
                    out[o] = fmaxf(val, 0.f);
                }
            }
        }
    }
}

extern "C" void kernel_launch(void* const* d_in, const int* in_sizes, int n_in,
                              void* d_out, int out_size, void* d_ws, size_t ws_size,
                              hipStream_t stream) {
    const float* x  = (const float*)d_in[0];
    const float* w1 = (const float*)d_in[1];
    const float* g1 = (const float*)d_in[2];
    const float* b1 = (const float*)d_in[3];
    const float* m1 = (const float*)d_in[4];
    const float* v1 = (const float*)d_in[5];
    const float* w2 = (const float*)d_in[6];
    const float* g2 = (const float*)d_in[7];
    const float* b2 = (const float*)d_in[8];
    const float* m2 = (const float*)d_in[9];
    const float* v2 = (const float*)d_in[10];

    // ws: wf1 | wf2 | bn(1024 f32) | yT (CHW us) | yT zero row (512 us)
    ushort* wf1 = (ushort*)d_ws;
    ushort* wf2 = wf1 + WELEM;
    float*  bn  = (float*)(wf2 + WELEM);
    ushort* yT  = (ushort*)(bn + 4 * C_CH);
    // d_out: xT (CHW us) | xT zero row (512 us); conv2 overwrites as fp32
    ushort* xT  = (ushort*)d_out;

    prep_kernel<<<dim3(4608), dim3(256), 0, stream>>>(
        w1, w2, g1, b1, m1, v1, g2, b2, m2, v2, wf1, wf2, bn,
        xT + ZBELEM, yT + ZBELEM);

    xpose_kernel<<<dim3(6272), dim3(256), 0, stream>>>(x, xT);

    conv_kernel<false><<<dim3(1568), dim3(256), 0, stream>>>(
        xT, wf1, bn, x, (void*)yT);

    conv_kernel<true><<<dim3(1568), dim3(256), 0, stream>>>(
        yT, wf2, bn + 512, x, d_out);
}

// Round 20
// 453.051 us; speedup vs baseline: 1.2951x; 1.2951x over previous
//
#include <hip/hip_runtime.h>
#include <hip/hip_bf16.h>

// BasicBlock via chunked shift-GEMM bf16 MFMA. R19 = R18 with the
// persistent-block zero-row bug fixed: conv1's epilogue transpose
// (T[64][264] = 16896 us) overwrites B[ZROW] (15360), so tiles after the
// first read garbage borders. Fix: re-zero ZROW in the per-tile prologue
// (between the two barriers). Else identical: grid 512 persistent (2
// blocks/CU), R16 per-tile body (rolled 4x18-step K-loop, depth-2 A
// prefetch, 1-tap bq dbuf, addr-select masking, counted-vmcnt chunk
// barriers, setprio, XCD swizzle).

typedef __attribute__((ext_vector_type(8))) short bf16x8;
typedef __attribute__((ext_vector_type(4))) float f32x4;
typedef __attribute__((ext_vector_type(4))) unsigned int uint4v;

#define C_CH   256
#define HW_IMG 3136
#define CHW    802816     // 256*3136
#define WELEM  589824     // 256*2304
#define RSTR   40         // LDS row stride in ushorts (32 data + 8 pad) = 80B
#define BUFE   7680       // 192*40 ushorts per buffer (15360B)
#define ZROW   15360      // zero row (40 ushorts) after both buffers

__device__ __forceinline__ ushort f2bf(float f){
    union{__hip_bfloat16 h; ushort u;} c; c.h = __float2bfloat16(f); return c.u;
}

__global__ __launch_bounds__(256) void prep_kernel(
    const float* __restrict__ w1, const float* __restrict__ w2,
    const float* __restrict__ g1, const float* __restrict__ b1,
    const float* __restrict__ m1, const float* __restrict__ v1,
    const float* __restrict__ g2, const float* __restrict__ b2,
    const float* __restrict__ m2, const float* __restrict__ v2,
    ushort* __restrict__ wf1, ushort* __restrict__ wf2,
    float* __restrict__ bn, ushort* __restrict__ zb)
{
    int gid = blockIdx.x * 256 + threadIdx.x;
    // frag-packed: d = (((c*9+r)*16 + ct)*64 + l)*8 + j
    // co = ct*16 + (l&15), ci = c*32 + (l>>4)*8 + j, tap r
    if (gid < WELEM) {
        int j = gid & 7, l = (gid >> 3) & 63, ct = (gid >> 9) & 15, rr = gid >> 13;
        int c = rr / 9, r = rr - c * 9;
        int co = ct * 16 + (l & 15);
        int ci = c * 32 + (l >> 4) * 8 + j;
        wf1[gid] = f2bf(w1[(co * C_CH + ci) * 9 + r]);
    }
    int g2i = gid - WELEM;
    if (g2i >= 0 && g2i < WELEM) {
        int j = g2i & 7, l = (g2i >> 3) & 63, ct = (g2i >> 9) & 15, rr = g2i >> 13;
        int c = rr / 9, r = rr - c * 9;
        int co = ct * 16 + (l & 15);
        int ci = c * 32 + (l >> 4) * 8 + j;
        wf2[g2i] = f2bf(w2[(co * C_CH + ci) * 9 + r]);
    }
    if (gid < C_CH) {
        float i1 = g1[gid] * rsqrtf(v1[gid] + 1e-5f);
        bn[gid]            = i1;
        bn[C_CH + gid]     = b1[gid] - m1[gid] * i1;
        float i2 = g2[gid] * rsqrtf(v2[gid] + 1e-5f);
        bn[2*C_CH + gid]   = i2;
        bn[3*C_CH + gid]   = b2[gid] - m2[gid] * i2;
    }
    if (gid < 512) zb[gid] = 0;
}

// x [n][ci][p] f32 -> xT [n][p][ci] bf16
__global__ __launch_bounds__(256) void xpose_kernel(
    const float* __restrict__ x, ushort* __restrict__ xT)
{
    __shared__ ushort T[64 * 72];
    int tid = threadIdx.x;
    int b = blockIdx.x;                  // 32*49*4
    int n = b / 196, rem = b % 196;
    int pb = rem >> 2, cb = rem & 3;
    int lane = tid & 63, cr = tid >> 6;
    const float* xp = x + ((size_t)(n * C_CH + cb * 64)) * HW_IMG + pb * 64 + lane;
#pragma unroll
    for (int j = 0; j < 16; ++j) {
        int cil = cr * 16 + j;
        T[lane * 72 + cil] = f2bf(xp[(size_t)cil * HW_IMG]);
    }
    __syncthreads();
#pragma unroll
    for (int it = 0; it < 2; ++it) {
        int slot = it * 256 + tid;       // 512 slots = 64 rows x 8 granules
        int p = slot >> 3, g = slot & 7;
        uint4v v = *(const uint4v*)&T[p * 72 + g * 8];
        *(uint4v*)(xT + ((size_t)n * HW_IMG + pb * 64 + p) * C_CH + cb * 64 + g * 8) = v;
    }
}

// read tap s's 4 B-frags into NAMED array `dst` (address-select zero row)
#define READB(dst, bufE, s)                                                  \
    {                                                                        \
        const int dw_ = (s) % 3 - 1;                                         \
        const int off_ = ((s) / 3 - 1) * 56 * RSTR + dw_ * RSTR + (bufE);    \
        _Pragma("unroll")                                                    \
        for (int nc_ = 0; nc_ < 4; ++nc_) {                                  \
            bool ok_ = (dw_ == -1) ? wLa[nc_]                                \
                                   : ((dw_ == 1) ? wRa[nc_] : true);         \
            int idx_ = ok_ ? (vbe[nc_] + off_) : zidx;                       \
            dst[nc_] = *(const bf16x8*)&B[idx_];                             \
        }                                                                    \
    }

// MFMA cluster; t is the BODY-RELATIVE step (0..17), compile-time
#define MFMA16(bq, t)                                                        \
    __builtin_amdgcn_s_setprio(1);                                           \
    _Pragma("unroll")                                                        \
    for (int mr_ = 0; mr_ < 4; ++mr_) {                                      \
        _Pragma("unroll")                                                    \
        for (int nc_ = 0; nc_ < 4; ++nc_)                                    \
            acc[mr_][nc_] = __builtin_amdgcn_mfma_f32_16x16x32_bf16(         \
                areg[(t) % 3][mr_], bq[nc_], acc[mr_][nc_], 0, 0, 0);        \
    }                                                                        \
    __builtin_amdgcn_s_setprio(0);

// load A-frags for body-relative step `toff` from runtime base pW
#define LOADA(toff, slot)                                                    \
    {                                                                        \
        _Pragma("unroll")                                                    \
        for (int mr_ = 0; mr_ < 4; ++mr_)                                    \
            areg[slot][mr_] = *(const bf16x8*)(pW + (toff) * 8192 + mr_ * 512);\
    }

// counted-vmcnt chunk barrier: own stage loads (older than the 20 A-loads
// issued at s=4..8) are retired; A-prefetches stay in flight (T4).
#define CHUNK_BAR()                                                          \
    asm volatile("s_waitcnt vmcnt(20)" ::: "memory");                        \
    __builtin_amdgcn_s_barrier();                                            \
    __builtin_amdgcn_sched_barrier(0);

template<bool SECOND>
__global__ __launch_bounds__(256, 2) void conv_kernel(
    const ushort* __restrict__ srcT,    // [n][p][ci] bf16
    const ushort* __restrict__ wf,      // frag-packed weights
    const float* __restrict__ bnp,      // inv | add
    const float* __restrict__ ident,    // x fp32 (conv2)
    const ushort* __restrict__ zb,
    void* __restrict__ dst)
{
    // dbuf 2*15360B + zero row; conv1 epilogue reuses as 64x264 transpose
    __shared__ ushort B[16896];

    const int tid = threadIdx.x;
    const int wv = tid >> 6, l = tid & 63;
    const int lr = l & 15, lg = l >> 4;
    const int bid = blockIdx.x;

    const int zidx = ZROW + lg * 8;      // zero-row read address
    const ushort* pW0 = wf + wv * 2048 + l * 8;

    // persistent: block handles tiles bid, bid+512, bid+1024 (+1536 if <32)
#pragma unroll 1
    for (int ti = bid; ti < 1568; ti += 512) {
        int swz = (ti & 7) * 196 + (ti >> 3);  // XCD-chunked, bijective
        const int n = swz / 49, pt = swz % 49;
        const int p0 = pt * 64;

        // W-border validity per nc (lane's output p = p0 + nc*16 + lr)
        bool wLa[4], wRa[4];
        int vbe[4];
#pragma unroll
        for (int nc = 0; nc < 4; ++nc) {
            int p = p0 + nc * 16 + lr;
            int w = p % 56;
            wLa[nc] = (w > 0);
            wRa[nc] = (w < 55);
            vbe[nc] = (64 + nc * 16 + lr) * RSTR + lg * 8;
        }

        // staging source ptrs: 960 slots of 16B per chunk; dest linear
        const ushort* sA[4];
#pragma unroll
        for (int rd = 0; rd < 4; ++rd) {
            int slot = rd * 256 + tid;
            int row = slot / 5, g = slot - row * 5;
            int gp = p0 - 64 + row;
            bool val = (g < 4) && (gp >= 0) && (gp < HW_IMG) && (slot < 960);
            sA[rd] = val ? (srcT + ((size_t)n * HW_IMG + gp) * C_CH + g * 8)
                         : (zb + g * 8);
        }

        auto stage = [&](int cix, int bufE) {
#pragma unroll
            for (int rd = 0; rd < 4; ++rd) {
                if (rd < 3 || tid < 192) {
                    __builtin_amdgcn_global_load_lds(
                        (const __attribute__((address_space(1))) void*)(sA[rd] + cix * 32),
                        (__attribute__((address_space(3))) void*)&B[bufE + (rd * 256 + tid) * 8],
                        16, 0, 0);
                }
            }
        };

        f32x4 acc[4][4];
#pragma unroll
        for (int mr = 0; mr < 4; ++mr)
#pragma unroll
            for (int nc = 0; nc < 4; ++nc) {
                f32x4 z = {0.f, 0.f, 0.f, 0.f};
                acc[mr][nc] = z;
            }

        bf16x8 areg[3][4];

        // per-tile prologue: protect LDS from prior tile's epilogue reads,
        // then stage chunk 0 AND re-zero the zero row (conv1's epilogue
        // transpose T[64][264] overwrites B[ZROW] -- R18's bug).
        __syncthreads();
        stage(0, 0);
        if (tid < 40) B[ZROW + tid] = 0;
        {
            const ushort* pW = pW0;
            LOADA(0, 0);
            LOADA(1, 1);
        }
        __syncthreads();   // drains stage (vmcnt0) + zero-row visible

        const ushort* pW = pW0;
        // 4 runtime iterations x (2 chunks = 18 steps); I-cache resident
#pragma unroll 1
        for (int c2 = 0; c2 < 4; ++c2) {
            // first half: chunk 2*c2, reads buf0; stage 2*c2+1 -> buf1
            {
                bf16x8 bqA[4], bqB[4];
                READB(bqA, 0, 0);
#pragma unroll
                for (int s = 0; s < 9; ++s) {
                    LOADA(s + 2, (s + 2) % 3);
                    if (s == 3) stage(2 * c2 + 1, BUFE);
                    if ((s & 1) == 0) {
                        if (s + 1 < 9) READB(bqB, 0, s + 1);
                        MFMA16(bqA, s);
                    } else {
                        READB(bqA, 0, s + 1);
                        MFMA16(bqB, s);
                    }
                }
            }
            CHUNK_BAR();
            // second half: chunk 2*c2+1, reads buf1; stage 2*c2+2 -> buf0
            {
                bf16x8 bqA[4], bqB[4];
                READB(bqA, BUFE, 0);
#pragma unroll
                for (int s = 0; s < 9; ++s) {
                    const int t = s + 9;
                    if (s < 7 || c2 < 3) LOADA(t + 2, (t + 2) % 3);
                    if (s == 3 && c2 < 3) stage(2 * c2 + 2, 0);
                    if ((s & 1) == 0) {
                        if (s + 1 < 9) READB(bqB, BUFE, s + 1);
                        MFMA16(bqA, t);
                    } else {
                        READB(bqA, BUFE, s + 1);
                        MFMA16(bqB, t);
                    }
                }
            }
            CHUNK_BAR();
            pW += 18 * 8192;
        }
        __syncthreads();   // full drain before epilogue LDS reuse

        if constexpr (!SECOND) {
            // epilogue: BN+ReLU, LDS-transpose to yT [n][p][co] bf16
            ushort* T = B;              // [64 p][264] (256 co + 8 pad)
#pragma unroll
            for (int mr = 0; mr < 4; ++mr) {
#pragma unroll
                for (int nc = 0; nc < 4; ++nc) {
                    int co0 = wv * 64 + mr * 16 + lg * 4;
                    float v0 = fmaxf(acc[mr][nc][0] * bnp[co0+0] + bnp[C_CH+co0+0], 0.f);
                    float v1 = fmaxf(acc[mr][nc][1] * bnp[co0+1] + bnp[C_CH+co0+1], 0.f);
                    float v2 = fmaxf(acc[mr][nc][2] * bnp[co0+2] + bnp[C_CH+co0+2], 0.f);
                    float v3 = fmaxf(acc[mr][nc][3] * bnp[co0+3] + bnp[C_CH+co0+3], 0.f);
                    uint2 pk;
                    pk.x = (uint)f2bf(v0) | ((uint)f2bf(v1) << 16);
                    pk.y = (uint)f2bf(v2) | ((uint)f2bf(v3) << 16);
                    *(uint2*)&T[(nc * 16 + lr) * 264 + co0] = pk;
                }
            }
            __syncthreads();
            ushort* yT = (ushort*)dst;
#pragma unroll
            for (int it = 0; it < 8; ++it) {
                int slot = it * 256 + tid;  // 2048 slots = 64 rows x 32 granules
                int row = slot >> 5, g = slot & 31;
                uint4v v = *(const uint4v*)&T[row * 264 + g * 8];
                *(uint4v*)(yT + ((size_t)n * HW_IMG + p0 + row) * C_CH + g * 8) = v;
            }
        } else {
            // epilogue: BN + identity + ReLU, fp32 out [n][co][p]
            const size_t nbase = (size_t)n * CHW;
            float* out = (float*)dst;
#pragma unroll
            for (int mr = 0; mr < 4; ++mr) {
#pragma unroll
                for (int nc = 0; nc < 4; ++nc) {
                    int pc = p0 + nc * 16 + lr;
#pragma unroll
                    for (int i = 0; i < 4; ++i) {
                        int co = wv * 64 + mr * 16 + lg * 4 + i;
                        size_t o = nbase + (size_t)co * HW_IMG + pc;
                        float val = acc[mr][nc][i] * bnp[co] + bnp[C_CH + co] + ident[o];
                        out[o] = fmaxf(val, 0.f);
                    }
                }
            }
        }
    }
}

extern "C" void kernel_launch(void* const* d_in, const int* in_sizes, int n_in,
                              void* d_out, int out_size, void* d_ws, size_t ws_size,
                              hipStream_t stream) {
    const float* x  = (const float*)d_in[0];
    const float* w1 = (const float*)d_in[1];
    const float* g1 = (const float*)d_in[2];
    const float* b1 = (const float*)d_in[3];
    const float* m1 = (const float*)d_in[4];
    const float* v1 = (const float*)d_in[5];
    const float* w2 = (const float*)d_in[6];
    const float* g2 = (const float*)d_in[7];
    const float* b2 = (const float*)d_in[8];
    const float* m2 = (const float*)d_in[9];
    const float* v2 = (const float*)d_in[10];

    ushort* wf1 = (ushort*)d_ws;
    ushort* wf2 = wf1 + WELEM;
    float*  bn  = (float*)(wf2 + WELEM);
    ushort* zb  = (ushort*)(bn + 4 * C_CH);
    ushort* yT  = zb + 512;
    ushort* xT  = (ushort*)d_out;   // scratch in d_out; conv2 overwrites fully

    prep_kernel<<<dim3(4608), dim3(256), 0, stream>>>(
        w1, w2, g1, b1, m1, v1, g2, b2, m2, v2, wf1, wf2, bn, zb);

    xpose_kernel<<<dim3(6272), dim3(256), 0, stream>>>(x, xT);

    conv_kernel<false><<<dim3(512), dim3(256), 0, stream>>>(
        xT, wf1, bn, x, zb, (void*)yT);

    conv_kernel<true><<<dim3(512), dim3(256), 0, stream>>>(
        yT, wf2, bn + 512, x, zb, d_out);
}

// Round 21
// 252.547 us; speedup vs baseline: 2.3234x; 1.7939x over previous
//
#include <hip/hip_runtime.h>
#include <hip/hip_bf16.h>

// BasicBlock via chunked shift-GEMM bf16 MFMA. FINAL = R14 (best measured:
// 251.9 us total, absmax 0.0625). Structure: per conv, output tile 256co x
// 64p per block (grid 1568, XCD-chunked swizzle), ci in 8 chunks of 32;
// per chunk a 192-row spatial window [p0-64,p0+128) x 32ci staged to LDS
// via global_load_lds (linear dest, 80B rows) at step s==3 (mid-chunk, so
// A-frag waits never drain fresh HBM stage loads); 9 tap-steps of
// ds_read+MFMA with compile-time tap offsets; depth-2 A-prefetch
// (areg[3], weights frag-packed by prep so fragments are contiguous);
// 1-tap B prefetch via macros on NAMED arrays (scratch-safe); border
// masking = address-select into an LDS zero row (pre-read, 1 cndmask);
// setprio around MFMA clusters; __launch_bounds__(256,2) (cap 256 regs:
// (256,3)'s ~168 cap spilled this pipeline, R6/R8 evidence).
// Sources bf16 [n][p][ci]: xT precomputed (scratch in d_out), conv1
// writes yT via LDS-transposed epilogue; conv2 adds identity + ReLU fp32.

typedef __attribute__((ext_vector_type(8))) short bf16x8;
typedef __attribute__((ext_vector_type(4))) float f32x4;
typedef __attribute__((ext_vector_type(4))) unsigned int uint4v;

#define C_CH   256
#define HW_IMG 3136
#define CHW    802816     // 256*3136
#define WELEM  589824     // 256*2304
#define RSTR   40         // LDS row stride in ushorts (32 data + 8 pad) = 80B
#define BUFE   7680       // 192*40 ushorts per buffer (15360B)
#define NCH    8          // ci chunks of 32
#define NSTEP  72         // 8 chunks * 9 taps
#define ZROW   15360      // zero row (40 ushorts) after both buffers

__device__ __forceinline__ ushort f2bf(float f){
    union{__hip_bfloat16 h; ushort u;} c; c.h = __float2bfloat16(f); return c.u;
}

__global__ __launch_bounds__(256) void prep_kernel(
    const float* __restrict__ w1, const float* __restrict__ w2,
    const float* __restrict__ g1, const float* __restrict__ b1,
    const float* __restrict__ m1, const float* __restrict__ v1,
    const float* __restrict__ g2, const float* __restrict__ b2,
    const float* __restrict__ m2, const float* __restrict__ v2,
    ushort* __restrict__ wf1, ushort* __restrict__ wf2,
    float* __restrict__ bn, ushort* __restrict__ zb)
{
    int gid = blockIdx.x * 256 + threadIdx.x;
    // frag-packed: d = (((c*9+r)*16 + ct)*64 + l)*8 + j
    // co = ct*16 + (l&15), ci = c*32 + (l>>4)*8 + j, tap r
    if (gid < WELEM) {
        int j = gid & 7, l = (gid >> 3) & 63, ct = (gid >> 9) & 15, rr = gid >> 13;
        int c = rr / 9, r = rr - c * 9;
        int co = ct * 16 + (l & 15);
        int ci = c * 32 + (l >> 4) * 8 + j;
        wf1[gid] = f2bf(w1[(co * C_CH + ci) * 9 + r]);
    }
    int g2i = gid - WELEM;
    if (g2i >= 0 && g2i < WELEM) {
        int j = g2i & 7, l = (g2i >> 3) & 63, ct = (g2i >> 9) & 15, rr = g2i >> 13;
        int c = rr / 9, r = rr - c * 9;
        int co = ct * 16 + (l & 15);
        int ci = c * 32 + (l >> 4) * 8 + j;
        wf2[g2i] = f2bf(w2[(co * C_CH + ci) * 9 + r]);
    }
    if (gid < C_CH) {
        float i1 = g1[gid] * rsqrtf(v1[gid] + 1e-5f);
        bn[gid]            = i1;
        bn[C_CH + gid]     = b1[gid] - m1[gid] * i1;
        float i2 = g2[gid] * rsqrtf(v2[gid] + 1e-5f);
        bn[2*C_CH + gid]   = i2;
        bn[3*C_CH + gid]   = b2[gid] - m2[gid] * i2;
    }
    if (gid < 512) zb[gid] = 0;
}

// x [n][ci][p] f32 -> xT [n][p][ci] bf16
__global__ __launch_bounds__(256) void xpose_kernel(
    const float* __restrict__ x, ushort* __restrict__ xT)
{
    __shared__ ushort T[64 * 72];
    int tid = threadIdx.x;
    int b = blockIdx.x;                  // 32*49*4
    int n = b / 196, rem = b % 196;
    int pb = rem >> 2, cb = rem & 3;
    int lane = tid & 63, cr = tid >> 6;
    const float* xp = x + ((size_t)(n * C_CH + cb * 64)) * HW_IMG + pb * 64 + lane;
#pragma unroll
    for (int j = 0; j < 16; ++j) {
        int cil = cr * 16 + j;
        T[lane * 72 + cil] = f2bf(xp[(size_t)cil * HW_IMG]);
    }
    __syncthreads();
#pragma unroll
    for (int it = 0; it < 2; ++it) {
        int slot = it * 256 + tid;       // 512 slots = 64 rows x 8 granules
        int p = slot >> 3, g = slot & 7;
        uint4v v = *(const uint4v*)&T[p * 72 + g * 8];
        *(uint4v*)(xT + ((size_t)n * HW_IMG + pb * 64 + p) * C_CH + cb * 64 + g * 8) = v;
    }
}

// read tap s's 4 B-frags into NAMED array `dst` (address-select zero row)
#define READB(dst, bufE, s)                                                  \
    {                                                                        \
        const int dw_ = (s) % 3 - 1;                                         \
        const int off_ = ((s) / 3 - 1) * 56 * RSTR + dw_ * RSTR + (bufE);    \
        _Pragma("unroll")                                                    \
        for (int nc_ = 0; nc_ < 4; ++nc_) {                                  \
            bool ok_ = (dw_ == -1) ? wLa[nc_]                                \
                                   : ((dw_ == 1) ? wRa[nc_] : true);         \
            int idx_ = ok_ ? (vbe[nc_] + off_) : zidx;                       \
            dst[nc_] = *(const bf16x8*)&B[idx_];                             \
        }                                                                    \
    }

#define MFMA16(bq, t)                                                        \
    __builtin_amdgcn_s_setprio(1);                                           \
    _Pragma("unroll")                                                        \
    for (int mr_ = 0; mr_ < 4; ++mr_) {                                      \
        _Pragma("unroll")                                                    \
        for (int nc_ = 0; nc_ < 4; ++nc_)                                    \
            acc[mr_][nc_] = __builtin_amdgcn_mfma_f32_16x16x32_bf16(         \
                areg[(t) % 3][mr_], bq[nc_], acc[mr_][nc_], 0, 0, 0);        \
    }                                                                        \
    __builtin_amdgcn_s_setprio(0);

template<bool SECOND>
__global__ __launch_bounds__(256, 2) void conv_kernel(
    const ushort* __restrict__ srcT,    // [n][p][ci] bf16
    const ushort* __restrict__ wf,      // frag-packed weights
    const float* __restrict__ bnp,      // inv | add
    const float* __restrict__ ident,    // x fp32 (conv2)
    const ushort* __restrict__ zb,
    void* __restrict__ dst)
{
    // dbuf 2*15360B + zero row; conv1 epilogue reuses as 64x264 transpose
    __shared__ ushort B[16896];

    const int tid = threadIdx.x;
    const int wv = tid >> 6, l = tid & 63;
    const int lr = l & 15, lg = l >> 4;

    int bid = blockIdx.x;
    int swz = (bid & 7) * 196 + (bid >> 3);   // XCD-chunked, bijective (1568=8*196)
    const int n = swz / 49, pt = swz % 49;
    const int p0 = pt * 64;

    // W-border validity per nc (lane's output p = p0 + nc*16 + lr)
    bool wLa[4], wRa[4];
    int vbe[4];
#pragma unroll
    for (int nc = 0; nc < 4; ++nc) {
        int p = p0 + nc * 16 + lr;
        int w = p % 56;
        wLa[nc] = (w > 0);
        wRa[nc] = (w < 55);
        vbe[nc] = (64 + nc * 16 + lr) * RSTR + lg * 8;   // B-frag LDS base (ushort)
    }
    const int zidx = ZROW + lg * 8;      // zero-row read address

    // staging: 960 slots of 16B per chunk; dest linear (row*80B+g*16B = slot*16B)
    const ushort* sA[4];
#pragma unroll
    for (int rd = 0; rd < 4; ++rd) {
        int slot = rd * 256 + tid;
        int row = slot / 5, g = slot - row * 5;
        int gp = p0 - 64 + row;
        bool val = (g < 4) && (gp >= 0) && (gp < HW_IMG) && (slot < 960);
        sA[rd] = val ? (srcT + ((size_t)n * HW_IMG + gp) * C_CH + g * 8)
                     : (zb + g * 8);
    }

    auto stage = [&](int cix, int bufE) {
#pragma unroll
        for (int rd = 0; rd < 4; ++rd) {
            if (rd < 3 || tid < 192) {
                __builtin_amdgcn_global_load_lds(
                    (const __attribute__((address_space(1))) void*)(sA[rd] + cix * 32),
                    (__attribute__((address_space(3))) void*)&B[bufE + (rd * 256 + tid) * 8],
                    16, 0, 0);
            }
        }
    };

    f32x4 acc[4][4];
#pragma unroll
    for (int mr = 0; mr < 4; ++mr)
#pragma unroll
        for (int nc = 0; nc < 4; ++nc) {
            f32x4 z = {0.f, 0.f, 0.f, 0.f};
            acc[mr][nc] = z;
        }

    bf16x8 areg[3][4];
    const ushort* pWb = wf + wv * 2048 + l * 8;   // + (c*9+r)*8192 + mr*512

    auto loadA = [&](int t, bf16x8* a) {          // t compile-time
#pragma unroll
        for (int mr = 0; mr < 4; ++mr)
            a[mr] = *(const bf16x8*)(pWb + t * 8192 + mr * 512);
    };

    // prologue
    stage(0, 0);
    if (tid < 40) B[ZROW + tid] = 0;
    loadA(0, areg[0]);
    loadA(1, areg[1]);
    __syncthreads();

#pragma unroll
    for (int c = 0; c < NCH; ++c) {
        const int bufE = (c & 1) ? BUFE : 0;
        bf16x8 bqA[4], bqB[4];
        READB(bqA, bufE, 0);
#pragma unroll
        for (int s = 0; s < 9; ++s) {
            const int t = c * 9 + s;
            if (t + 2 < NSTEP) loadA(t + 2, areg[(t + 2) % 3]);
            if (s == 3 && c + 1 < NCH) stage(c + 1, bufE ^ BUFE);
            if ((s & 1) == 0) {
                if (s + 1 < 9) READB(bqB, bufE, s + 1);
                MFMA16(bqA, t);
            } else {
                READB(bqA, bufE, s + 1);   // s+1 <= 8
                MFMA16(bqB, t);
            }
        }
        __syncthreads();
    }

    if constexpr (!SECOND) {
        // epilogue: BN+ReLU, LDS-transpose to yT [n][p][co] bf16
        ushort* T = B;                  // [64 p][264] (256 co + 8 pad)
#pragma unroll
        for (int mr = 0; mr < 4; ++mr) {
#pragma unroll
            for (int nc = 0; nc < 4; ++nc) {
                int co0 = wv * 64 + mr * 16 + lg * 4;
                float v0 = fmaxf(acc[mr][nc][0] * bnp[co0+0] + bnp[C_CH+co0+0], 0.f);
                float v1 = fmaxf(acc[mr][nc][1] * bnp[co0+1] + bnp[C_CH+co0+1], 0.f);
                float v2 = fmaxf(acc[mr][nc][2] * bnp[co0+2] + bnp[C_CH+co0+2], 0.f);
                float v3 = fmaxf(acc[mr][nc][3] * bnp[co0+3] + bnp[C_CH+co0+3], 0.f);
                uint2 pk;
                pk.x = (uint)f2bf(v0) | ((uint)f2bf(v1) << 16);
                pk.y = (uint)f2bf(v2) | ((uint)f2bf(v3) << 16);
                *(uint2*)&T[(nc * 16 + lr) * 264 + co0] = pk;
            }
        }
        __syncthreads();
        ushort* yT = (ushort*)dst;
#pragma unroll
        for (int it = 0; it < 8; ++it) {
            int slot = it * 256 + tid;  // 2048 slots = 64 rows x 32 granules
            int row = slot >> 5, g = slot & 31;
            uint4v v = *(const uint4v*)&T[row * 264 + g * 8];
            *(uint4v*)(yT + ((size_t)n * HW_IMG + p0 + row) * C_CH + g * 8) = v;
        }
    } else {
        // epilogue: BN + identity + ReLU, fp32 out [n][co][p]
        const size_t nbase = (size_t)n * CHW;
        float* out = (float*)dst;
#pragma unroll
        for (int mr = 0; mr < 4; ++mr) {
#pragma unroll
            for (int nc = 0; nc < 4; ++nc) {
                int pc = p0 + nc * 16 + lr;
#pragma unroll
                for (int i = 0; i < 4; ++i) {
                    int co = wv * 64 + mr * 16 + lg * 4 + i;
                    size_t o = nbase + (size_t)co * HW_IMG + pc;
                    float val = acc[mr][nc][i] * bnp[co] + bnp[C_CH + co] + ident[o];
                    out[o] = fmaxf(val, 0.f);
                }
            }
        }
    }
}

extern "C" void kernel_launch(void* const* d_in, const int* in_sizes, int n_in,
                              void* d_out, int out_size, void* d_ws, size_t ws_size,
                              hipStream_t stream) {
    const float* x  = (const float*)d_in[0];
    const float* w1 = (const float*)d_in[1];
    const float* g1 = (const float*)d_in[2];
    const float* b1 = (const float*)d_in[3];
    const float* m1 = (const float*)d_in[4];
    const float* v1 = (const float*)d_in[5];
    const float* w2 = (const float*)d_in[6];
    const float* g2 = (const float*)d_in[7];
    const float* b2 = (const float*)d_in[8];
    const float* m2 = (const float*)d_in[9];
    const float* v2 = (const float*)d_in[10];

    ushort* wf1 = (ushort*)d_ws;
    ushort* wf2 = wf1 + WELEM;
    float*  bn  = (float*)(wf2 + WELEM);
    ushort* zb  = (ushort*)(bn + 4 * C_CH);
    ushort* yT  = zb + 512;
    ushort* xT  = (ushort*)d_out;   // scratch in d_out; conv2 overwrites fully

    prep_kernel<<<dim3(4608), dim3(256), 0, stream>>>(
        w1, w2, g1, b1, m1, v1, g2, b2, m2, v2, wf1, wf2, bn, zb);

    xpose_kernel<<<dim3(6272), dim3(256), 0, stream>>>(x, xT);

    conv_kernel<false><<<dim3(1568), dim3(256), 0, stream>>>(
        xT, wf1, bn, x, zb, (void*)yT);

    conv_kernel<true><<<dim3(1568), dim3(256), 0, stream>>>(
        yT, wf2, bn + 512, x, zb, d_out);
}